// Round 3
// baseline (116.589 us; speedup 1.0000x reference)
//
#include <hip/hip_runtime.h>
#include <hip/hip_bf16.h>

typedef __attribute__((ext_vector_type(8))) short short8;
typedef __attribute__((ext_vector_type(4))) float f32x4;

#define B_ 8
#define N_ 4096
#define E_ 16384
#define K_ 16
#define F_ 128

__device__ __forceinline__ float bf2f(unsigned short h) {
    unsigned int u = ((unsigned int)h) << 16;
    union { unsigned int u; float f; } c; c.u = u; return c.f;
}
__device__ __forceinline__ unsigned short f2bf(float f) {
    union { float f; unsigned int u; } c; c.f = f;
    unsigned int u = c.u;
    unsigned int r = (u + 0x7fffu + ((u >> 16) & 1u)) >> 16;
    return (unsigned short)r;
}
__device__ __forceinline__ float fast_tanh(float x) {
    float e = __expf(2.0f * x);
    return 1.0f - 2.0f / (e + 1.0f);
}

// ---- detect whether an "integer" input buffer is int64 (high words all 0) ----
__device__ __forceinline__ int detect64(const int* raw) {
    int o = 0;
    #pragma unroll
    for (int i = 1; i < 128; i += 2) o |= raw[i];
    return (o == 0) ? 1 : 0;
}

// sender[i] = edges[b,e,0]  (stride 3), handling int32 or int64 source
__global__ void conv_sender(const int* __restrict__ raw, int* __restrict__ dst) {
    __shared__ int s64;
    if (threadIdx.x == 0) s64 = detect64(raw);
    __syncthreads();
    int i = blockIdx.x * 256 + threadIdx.x;
    if (i < B_ * E_) {
        dst[i] = s64 ? raw[6 * (long long)i] : raw[3 * (long long)i];
    }
}

// pne[i] = mask[i] ? node_edges[i] : -1   (handles int32/int64 node_edges)
__global__ void conv_ne(const int* __restrict__ raw, const int* __restrict__ mask,
                        int* __restrict__ pne) {
    __shared__ int s64;
    if (threadIdx.x == 0) s64 = detect64(raw);
    __syncthreads();
    int i = blockIdx.x * 256 + threadIdx.x;
    if (i < B_ * N_ * K_) {
        int eid = s64 ? raw[2 * (long long)i] : raw[i];
        pne[i] = mask[i] ? eid : -1;
    }
}

// Pre-swizzle W1,W2 into MFMA B-operand (K x N tile) fragment order (bf16):
// for tile nt, lane l, t: wf[((nt*4+g)*64+l)*8+t] = W[nt*16+(l&15)][g*32+8*(l>>4)+t]
__global__ void wprep(const float* __restrict__ W1, const float* __restrict__ W2,
                      unsigned short* __restrict__ wf) {
    int tid = blockIdx.x * 256 + threadIdx.x;  // 0..4095
    int wsel = tid >> 11;
    int q = tid & 2047;
    int lane = q & 63;
    int gq = q >> 6;          // nt*4+g
    int nt = gq >> 2, g = gq & 3;
    const float* W = wsel ? W2 : W1;
    int j = nt * 16 + (lane & 15);
    int kbase = g * 32 + 8 * (lane >> 4);
    unsigned short* d = wf + wsel * 16384 + q * 8;
    #pragma unroll
    for (int t = 0; t < 8; ++t) d[t] = f2bf(W[j * 128 + kbase + t]);
}

// x0 -> out[:, :, 0:128] (fp32) and xb (bf16)
__global__ void prep_x0(const float* __restrict__ x0, float* __restrict__ out,
                        unsigned short* __restrict__ xb) {
    long long gid = (long long)blockIdx.x * 256 + threadIdx.x;  // < B*N*F/4
    long long flat = gid * 4;
    long long bn = flat >> 7;
    int j = (int)(flat & 127);
    float4 v = *(const float4*)(x0 + flat);
    *(float4*)(out + bn * 384 + j) = v;
    ushort4 h;
    h.x = f2bf(v.x); h.y = f2bf(v.y); h.z = f2bf(v.z); h.w = f2bf(v.w);
    *(ushort4*)(xb + flat) = h;
}

// Fused message-passing round:
// x_next[n,:] = ( sum_k mask * tanh( x[sender[pne[n,k]],:] @ W^T + b ) ) / (cnt+eps)
// Block = 4 waves = 4 nodes. 64 (node,k) instances' sender rows staged in LDS
// (chunk-XOR swizzle). Wave w computes j-slice nt in {2w,2w+1} with persistent
// W fragments in VGPRs; D[inst][j] via mfma(A=x_rows, B=W^T); tanh+mask per
// instance; aggregation = 2x shfl_xor reduce over the 16 inst rows.
__global__ void __launch_bounds__(256) fused_mp(
    const unsigned short* __restrict__ xb, const int* __restrict__ sender,
    const int* __restrict__ pne, const unsigned short* __restrict__ wf,
    const float* __restrict__ bias, float* __restrict__ out,
    unsigned short* __restrict__ xbn, int col_off) {
    __shared__ short xt[64 * F_];   // 16 KB
    __shared__ int sidx[64];
    __shared__ float msk[64];
    __shared__ float cinv[4];
    int tid = threadIdx.x;
    int blk = blockIdx.x;
    int node0 = blk * 4;
    int b = node0 >> 12;            // N=4096, blocks never straddle batches
    // phase 1: wave 0 resolves indices + per-node 1/(cnt+eps)
    if (tid < 64) {
        int pk = pne[node0 * K_ + tid];
        float m = (pk >= 0) ? 1.0f : 0.0f;
        sidx[tid] = (pk >= 0) ? sender[b * E_ + pk] : 0;
        msk[tid] = m;
        float c = m;
        c += __shfl_xor(c, 1); c += __shfl_xor(c, 2);
        c += __shfl_xor(c, 4); c += __shfl_xor(c, 8);
        if ((tid & 15) == 0) cinv[tid >> 4] = 1.0f / (c + 1e-8f);
    }
    __syncthreads();
    // phase 2: stage 64 rows (256B each) into LDS, 16B chunks, pch = ch ^ (row&15)
    #pragma unroll
    for (int c = 0; c < 4; ++c) {
        int ci = tid + 256 * c;         // 0..1023
        int row = ci >> 4, ch = ci & 15;
        int pch = ch ^ (row & 15);
        const int4* src = (const int4*)(xb + ((long long)(b * N_ + sidx[row])) * F_ + ch * 8);
        *(int4*)&xt[row * F_ + pch * 8] = *src;
    }
    __syncthreads();
    int w = tid >> 6, lane = tid & 63;
    int q = lane >> 4, r0 = lane & 15;
    // persistent W fragments: this wave's 2 j-tiles
    short8 wreg[2][4];
    #pragma unroll
    for (int h = 0; h < 2; ++h)
        #pragma unroll
        for (int g = 0; g < 4; ++g)
            wreg[h][g] = *(const short8*)(wf + (((2 * w + h) * 4 + g) * 64 + lane) * 8);
    float bcol[2];
    bcol[0] = bias[(2 * w + 0) * 16 + r0];
    bcol[1] = bias[(2 * w + 1) * 16 + r0];
    #pragma unroll
    for (int nn = 0; nn < 4; ++nn) {
        int rr = nn * 16 + r0;          // this lane's A-row (inst) in LDS
        short8 afr[4];
        #pragma unroll
        for (int g = 0; g < 4; ++g) {
            int pch = (g * 4 + q) ^ (rr & 15);
            afr[g] = *(const short8*)&xt[rr * F_ + pch * 8];
        }
        float m0 = msk[nn * 16 + q * 4 + 0];
        float m1 = msk[nn * 16 + q * 4 + 1];
        float m2 = msk[nn * 16 + q * 4 + 2];
        float m3 = msk[nn * 16 + q * 4 + 3];
        float ci = cinv[nn];
        float s[2];
        #pragma unroll
        for (int h = 0; h < 2; ++h) {
            f32x4 acc = (f32x4){0.f, 0.f, 0.f, 0.f};
            #pragma unroll
            for (int g = 0; g < 4; ++g)
                acc = __builtin_amdgcn_mfma_f32_16x16x32_bf16(afr[g], wreg[h][g], acc, 0, 0, 0);
            // D layout: col = lane&15 (j), row = q*4+r (inst)
            float sv;
            sv  = m0 * fast_tanh(acc[0] + bcol[h]);
            sv += m1 * fast_tanh(acc[1] + bcol[h]);
            sv += m2 * fast_tanh(acc[2] + bcol[h]);
            sv += m3 * fast_tanh(acc[3] + bcol[h]);
            sv += __shfl_xor(sv, 16);
            sv += __shfl_xor(sv, 32);
            s[h] = sv * ci;
        }
        int node = node0 + nn;
        if (q < 2) {                     // lanes 0-31 write both j-tiles
            int col = (2 * w + q) * 16 + r0;
            float val = q ? s[1] : s[0];
            out[(long long)node * 384 + col_off + col] = val;
            if (xbn) xbn[(long long)node * F_ + col] = f2bf(val);
        }
    }
}

extern "C" void kernel_launch(void* const* d_in, const int* in_sizes, int n_in,
                              void* d_out, int out_size, void* d_ws, size_t ws_size,
                              hipStream_t stream) {
    const float* x0        = (const float*)d_in[0];
    const int*   edges_raw = (const int*)d_in[1];
    const int*   ne_raw    = (const int*)d_in[2];
    const int*   mask      = (const int*)d_in[3];
    const float* W1        = (const float*)d_in[4];
    const float* b1        = (const float*)d_in[5];
    const float* W2        = (const float*)d_in[6];
    const float* b2        = (const float*)d_in[7];
    float* out = (float*)d_out;
    char* ws = (char*)d_ws;

    unsigned short* xb   = (unsigned short*)ws;                   // B*N*F bf16 = 8 MB
    unsigned short* x1b  = (unsigned short*)(ws + 8388608);       // B*N*F bf16 = 8 MB
    unsigned short* wf   = (unsigned short*)(ws + 16777216);      // 2*128*128  = 64 KB
    int* sender32        = (int*)(ws + 16842752);                 // B*E int32  = 512 KB
    int* pne             = (int*)(ws + 17367040);                 // B*N*K      = 2 MB

    conv_sender<<<512, 256, 0, stream>>>(edges_raw, sender32);
    conv_ne<<<2048, 256, 0, stream>>>(ne_raw, mask, pne);
    wprep<<<16, 256, 0, stream>>>(W1, W2, wf);
    prep_x0<<<4096, 256, 0, stream>>>(x0, out, xb);

    // round 1: reads xb, writes out[:,:,128:256] and x1b
    fused_mp<<<8192, 256, 0, stream>>>(xb, sender32, pne, wf, b1, out, x1b, 128);
    // round 2: reads x1b, writes out[:,:,256:384]
    fused_mp<<<8192, 256, 0, stream>>>(x1b, sender32, pne, wf + 16384, b2, out, nullptr, 256);
}

// Round 4
// 94.635 us; speedup vs baseline: 1.2320x; 1.2320x over previous
//
#include <hip/hip_runtime.h>
#include <hip/hip_bf16.h>

typedef __attribute__((ext_vector_type(8))) short short8;
typedef __attribute__((ext_vector_type(4))) float f32x4;

#define B_ 8
#define N_ 4096
#define E_ 16384
#define K_ 16
#define F_ 128

__device__ __forceinline__ float bf2f(unsigned short h) {
    unsigned int u = ((unsigned int)h) << 16;
    union { unsigned int u; float f; } c; c.u = u; return c.f;
}
__device__ __forceinline__ unsigned short f2bf(float f) {
    union { float f; unsigned int u; } c; c.f = f;
    unsigned int u = c.u;
    unsigned int r = (u + 0x7fffu + ((u >> 16) & 1u)) >> 16;
    return (unsigned short)r;
}
__device__ __forceinline__ float fast_tanh(float x) {
    float e = __expf(2.0f * x);
    return 1.0f - 2.0f / (e + 1.0f);
}

// ---- detect whether an "integer" input buffer is int64 (high words all 0) ----
__device__ __forceinline__ int detect64(const int* raw) {
    int o = 0;
    #pragma unroll
    for (int i = 1; i < 128; i += 2) o |= raw[i];
    return (o == 0) ? 1 : 0;
}

// One launch, partitioned grid:
//   blocks [0,512):     sender[i] = edges[b,e,0]        (handles i32/i64)
//   blocks [512,2560):  pne[i] = mask[i] ? ne[i] : -1   (handles i32/i64)
//   blocks [2560,2576): wf = W1,W2 in MFMA fragment order (bf16)
//     wf[((nt*4+g)*64+l)*8+t] = W[nt*16+(l&15)][g*32+8*(l>>4)+t]
__global__ void prep_idx(const int* __restrict__ edges_raw,
                         const int* __restrict__ ne_raw,
                         const int* __restrict__ mask,
                         const float* __restrict__ W1, const float* __restrict__ W2,
                         int* __restrict__ sender, int* __restrict__ pne,
                         unsigned short* __restrict__ wf) {
    int blk = blockIdx.x, tid = threadIdx.x;
    if (blk < 512) {
        __shared__ int s64;
        if (tid == 0) s64 = detect64(edges_raw);
        __syncthreads();
        int i = blk * 256 + tid;
        if (i < B_ * E_)
            sender[i] = s64 ? edges_raw[6 * (long long)i] : edges_raw[3 * (long long)i];
    } else if (blk < 2560) {
        __shared__ int s64;
        if (tid == 0) s64 = detect64(ne_raw);
        __syncthreads();
        int i = (blk - 512) * 256 + tid;
        if (i < B_ * N_ * K_) {
            int eid = s64 ? ne_raw[2 * (long long)i] : ne_raw[i];
            pne[i] = mask[i] ? eid : -1;
        }
    } else {
        int gtid = (blk - 2560) * 256 + tid;   // 0..4095
        int wsel = gtid >> 11;
        int q = gtid & 2047;
        int lane = q & 63;
        int gq = q >> 6;
        int nt = gq >> 2, g = gq & 3;
        const float* W = wsel ? W2 : W1;
        int j = nt * 16 + (lane & 15);
        int kbase = g * 32 + 8 * (lane >> 4);
        unsigned short* d = wf + wsel * 16384 + q * 8;
        #pragma unroll
        for (int t = 0; t < 8; ++t) d[t] = f2bf(W[j * 128 + kbase + t]);
    }
}

// edge_emb[b,e,:] = bf16( tanh( x[b,sender(e),:] @ W^T + bias ) )
// 64 edges/block, 4 waves. A=W (from wf), B=x^T -> D[j][edge];
// lane's 4 acc regs are consecutive j -> 8B ushort4 stores.
// SRC32: gather fp32 rows and convert during LDS staging; else bf16 rows.
template <int SRC32>
__global__ void __launch_bounds__(256) edge_kernel(
    const void* __restrict__ xsrc, const int* __restrict__ sender,
    const unsigned short* __restrict__ wf, const float* __restrict__ bias,
    unsigned short* __restrict__ eout) {
    __shared__ short xt[64 * F_];   // 16 KB, chunk-swizzled
    __shared__ int sids[64];
    int tid = threadIdx.x;
    int blk = blockIdx.x;
    int b = (blk * 64) / E_;
    int e0 = (blk * 64) % E_;
    if (tid < 64) sids[tid] = sender[b * E_ + e0 + tid];
    __syncthreads();
    // stage 64 rows into LDS as bf16; 16B chunks, pch = ch ^ (row&15)
    #pragma unroll
    for (int c = 0; c < 4; ++c) {
        int ci = tid + 256 * c;         // 0..1023
        int row = ci >> 4, ch = ci & 15;
        int pch = ch ^ (row & 15);
        if (SRC32) {
            const float* src = (const float*)xsrc + ((long long)(b * N_ + sids[row])) * F_ + ch * 8;
            float4 v0 = *(const float4*)src;
            float4 v1 = *(const float4*)(src + 4);
            ushort4 h0, h1;
            h0.x = f2bf(v0.x); h0.y = f2bf(v0.y); h0.z = f2bf(v0.z); h0.w = f2bf(v0.w);
            h1.x = f2bf(v1.x); h1.y = f2bf(v1.y); h1.z = f2bf(v1.z); h1.w = f2bf(v1.w);
            *(ushort4*)&xt[row * F_ + pch * 8] = h0;
            *(ushort4*)&xt[row * F_ + pch * 8 + 4] = h1;
        } else {
            const int4* src = (const int4*)((const unsigned short*)xsrc +
                                ((long long)(b * N_ + sids[row])) * F_ + ch * 8);
            *(int4*)&xt[row * F_ + pch * 8] = *src;
        }
    }
    __syncthreads();
    int w = tid >> 6, lane = tid & 63;
    int erow = w * 16 + (lane & 15);      // this wave's 16 edges
    short8 bfr[4];
    #pragma unroll
    for (int g = 0; g < 4; ++g) {
        int pch = (g * 4 + (lane >> 4)) ^ (erow & 15);
        bfr[g] = *(const short8*)&xt[erow * F_ + pch * 8];
    }
    int jq = (lane >> 4) * 4;             // j sub-offset of this lane's 4 regs
    long long ebase = ((long long)(b * E_ + e0 + w * 16 + (lane & 15))) * F_;
    #pragma unroll
    for (int nt = 0; nt < 8; ++nt) {
        f32x4 acc = (f32x4){0.f, 0.f, 0.f, 0.f};
        #pragma unroll
        for (int g = 0; g < 4; ++g) {
            short8 afr = *(const short8*)(wf + ((nt * 4 + g) * 64 + lane) * 8);
            acc = __builtin_amdgcn_mfma_f32_16x16x32_bf16(afr, bfr[g], acc, 0, 0, 0);
        }
        float4 bv = *(const float4*)(bias + nt * 16 + jq);
        ushort4 o;
        o.x = f2bf(fast_tanh(acc[0] + bv.x));
        o.y = f2bf(fast_tanh(acc[1] + bv.y));
        o.z = f2bf(fast_tanh(acc[2] + bv.z));
        o.w = f2bf(fast_tanh(acc[3] + bv.w));
        *(ushort4*)(eout + ebase + nt * 16 + jq) = o;
    }
}

// x_next[b,n,:] = sum_k mask * edge_emb[b, ne[n,k], :] / (cnt + eps)
// one wave per node; half-wave k-split (lanes 0-31 even k, 32-63 odd k);
// each lane covers 4 cols (8B). Branchless. If x0 != null, also copy
// x0[node,:] -> out[node, 0:128] (fp32).
__global__ void __launch_bounds__(256) agg_kernel(
    const unsigned short* __restrict__ ee, const int* __restrict__ pne,
    const float* __restrict__ x0, float* __restrict__ out,
    unsigned short* __restrict__ xbn, int col_off) {
    int wid = threadIdx.x >> 6, lane = threadIdx.x & 63;
    int node = blockIdx.x * 4 + wid;   // < B*N
    int b = node >> 12;                // N=4096
    if (x0) {
        float2 c = *(const float2*)(x0 + (long long)node * F_ + lane * 2);
        *(float2*)(out + (long long)node * 384 + lane * 2) = c;
    }
    const int4* q = (const int4*)(pne + node * K_);
    int4 q0 = q[0], q1 = q[1], q2 = q[2], q3 = q[3];
    int half = lane >> 5, sub = lane & 31;
    float cntf = (float)((q0.x >= 0) + (q0.y >= 0) + (q0.z >= 0) + (q0.w >= 0) +
                         (q1.x >= 0) + (q1.y >= 0) + (q1.z >= 0) + (q1.w >= 0) +
                         (q2.x >= 0) + (q2.y >= 0) + (q2.z >= 0) + (q2.w >= 0) +
                         (q3.x >= 0) + (q3.y >= 0) + (q3.z >= 0) + (q3.w >= 0));
    const unsigned short* ebase = ee + (long long)b * (E_ * F_) + sub * 4;
    float a0 = 0.f, a1 = 0.f, a2 = 0.f, a3 = 0.f;
    #define PROC(pe, po) { \
        int pk = half ? (po) : (pe); \
        float m = (pk >= 0) ? 1.0f : 0.0f; \
        int eid = pk < 0 ? 0 : pk; \
        ushort4 v = *(const ushort4*)(ebase + (long long)eid * F_); \
        a0 += m * bf2f(v.x); a1 += m * bf2f(v.y); \
        a2 += m * bf2f(v.z); a3 += m * bf2f(v.w); }
    PROC(q0.x, q0.y) PROC(q0.z, q0.w)
    PROC(q1.x, q1.y) PROC(q1.z, q1.w)
    PROC(q2.x, q2.y) PROC(q2.z, q2.w)
    PROC(q3.x, q3.y) PROC(q3.z, q3.w)
    #undef PROC
    a0 += __shfl_xor(a0, 32);
    a1 += __shfl_xor(a1, 32);
    a2 += __shfl_xor(a2, 32);
    a3 += __shfl_xor(a3, 32);
    if (half == 0) {
        float inv = 1.0f / (cntf + 1e-8f);
        a0 *= inv; a1 *= inv; a2 *= inv; a3 *= inv;
        float4 o; o.x = a0; o.y = a1; o.z = a2; o.w = a3;
        *(float4*)(out + (long long)node * 384 + col_off + sub * 4) = o;
        if (xbn) {
            ushort4 h;
            h.x = f2bf(a0); h.y = f2bf(a1); h.z = f2bf(a2); h.w = f2bf(a3);
            *(ushort4*)(xbn + (long long)node * F_ + sub * 4) = h;
        }
    }
}

extern "C" void kernel_launch(void* const* d_in, const int* in_sizes, int n_in,
                              void* d_out, int out_size, void* d_ws, size_t ws_size,
                              hipStream_t stream) {
    const float* x0        = (const float*)d_in[0];
    const int*   edges_raw = (const int*)d_in[1];
    const int*   ne_raw    = (const int*)d_in[2];
    const int*   mask      = (const int*)d_in[3];
    const float* W1        = (const float*)d_in[4];
    const float* b1        = (const float*)d_in[5];
    const float* W2        = (const float*)d_in[6];
    const float* b2        = (const float*)d_in[7];
    float* out = (float*)d_out;
    char* ws = (char*)d_ws;

    unsigned short* ebuf = (unsigned short*)ws;                   // B*E*F bf16 = 32 MB
    unsigned short* x1b  = (unsigned short*)(ws + 33554432);      // B*N*F bf16 = 8 MB
    unsigned short* wf   = (unsigned short*)(ws + 41943040);      // 2*128*128  = 64 KB
    int* sender32        = (int*)(ws + 42008576);                 // B*E int32  = 512 KB
    int* pne             = (int*)(ws + 42532864);                 // B*N*K      = 2 MB

    prep_idx<<<2576, 256, 0, stream>>>(edges_raw, ne_raw, mask, W1, W2,
                                       sender32, pne, wf);
    // round 1: edge transform from fp32 x0, agg also copies x0 -> out[:,0:128]
    edge_kernel<1><<<2048, 256, 0, stream>>>(x0, sender32, wf, b1, ebuf);
    agg_kernel<<<8192, 256, 0, stream>>>(ebuf, pne, x0, out, x1b, 128);
    // round 2
    edge_kernel<0><<<2048, 256, 0, stream>>>(x1b, sender32, wf + 16384, b2, ebuf);
    agg_kernel<<<8192, 256, 0, stream>>>(ebuf, pne, nullptr, out, nullptr, 256);
}

// Round 5
// 82.728 us; speedup vs baseline: 1.4093x; 1.1439x over previous
//
#include <hip/hip_runtime.h>
#include <hip/hip_bf16.h>

typedef __attribute__((ext_vector_type(8))) short short8;
typedef __attribute__((ext_vector_type(4))) float f32x4;

#define B_ 8
#define N_ 4096
#define E_ 16384
#define K_ 16
#define F_ 128

__device__ __forceinline__ float bf2f(unsigned short h) {
    unsigned int u = ((unsigned int)h) << 16;
    union { unsigned int u; float f; } c; c.u = u; return c.f;
}
__device__ __forceinline__ unsigned short f2bf(float f) {
    union { float f; unsigned int u; } c; c.f = f;
    unsigned int u = c.u;
    unsigned int r = (u + 0x7fffu + ((u >> 16) & 1u)) >> 16;
    return (unsigned short)r;
}
__device__ __forceinline__ float fast_tanh(float x) {
    float e = __expf(2.0f * x);
    return 1.0f - 2.0f / (e + 1.0f);
}

// ---- detect whether an "integer" input buffer is int64 (high words all 0) ----
__device__ __forceinline__ int detect64(const int* raw) {
    int o = 0;
    #pragma unroll
    for (int i = 1; i < 128; i += 2) o |= raw[i];
    return (o == 0) ? 1 : 0;
}

// One launch, partitioned grid:
//   blocks [0,512):     sender[i] = edges[b,e,0]        (handles i32/i64)
//   blocks [512,2560):  pne[i] = mask[i] ? ne[i] : -1   (handles i32/i64)
//   blocks [2560,2576): wf = W1,W2 in MFMA fragment order (bf16)
//     wf[((nt*4+g)*64+l)*8+t] = W[nt*16+(l&15)][g*32+8*(l>>4)+t]
__global__ void prep_idx(const int* __restrict__ edges_raw,
                         const int* __restrict__ ne_raw,
                         const int* __restrict__ mask,
                         const float* __restrict__ W1, const float* __restrict__ W2,
                         int* __restrict__ sender, int* __restrict__ pne,
                         unsigned short* __restrict__ wf) {
    int blk = blockIdx.x, tid = threadIdx.x;
    if (blk < 512) {
        __shared__ int s64;
        if (tid == 0) s64 = detect64(edges_raw);
        __syncthreads();
        int i = blk * 256 + tid;
        if (i < B_ * E_)
            sender[i] = s64 ? edges_raw[6 * (long long)i] : edges_raw[3 * (long long)i];
    } else if (blk < 2560) {
        __shared__ int s64;
        if (tid == 0) s64 = detect64(ne_raw);
        __syncthreads();
        int i = (blk - 512) * 256 + tid;
        if (i < B_ * N_ * K_) {
            int eid = s64 ? ne_raw[2 * (long long)i] : ne_raw[i];
            pne[i] = mask[i] ? eid : -1;
        }
    } else {
        int gtid = (blk - 2560) * 256 + tid;   // 0..4095
        int wsel = gtid >> 11;
        int q = gtid & 2047;
        int lane = q & 63;
        int gq = q >> 6;
        int nt = gq >> 2, g = gq & 3;
        const float* W = wsel ? W2 : W1;
        int j = nt * 16 + (lane & 15);
        int kbase = g * 32 + 8 * (lane >> 4);
        unsigned short* d = wf + wsel * 16384 + q * 8;
        #pragma unroll
        for (int t = 0; t < 8; ++t) d[t] = f2bf(W[j * 128 + kbase + t]);
    }
}

// edge_emb[b,e,:] = bf16( tanh( x[b,sender(e),:] @ W^T + bias ) )
// 64 edges/block, 4 waves. A=W (from wf), B=x^T -> D[j][edge];
// XCD-swizzled blocks: XCD x processes only batch x (B_ == 8 XCDs) so all
// x-row gathers stay in that XCD's L2.
template <int SRC32>
__global__ void __launch_bounds__(256) edge_kernel(
    const void* __restrict__ xsrc, const int* __restrict__ sender,
    const unsigned short* __restrict__ wf, const float* __restrict__ bias,
    unsigned short* __restrict__ eout) {
    __shared__ short xt[64 * F_];   // 16 KB, chunk-swizzled
    __shared__ int sids[64];
    int tid = threadIdx.x;
    int swz = (blockIdx.x & 7) * 256 + (blockIdx.x >> 3);   // batch-per-XCD
    int b = swz >> 8;
    int e0 = (swz & 255) * 64;
    if (tid < 64) sids[tid] = sender[b * E_ + e0 + tid];
    __syncthreads();
    // stage 64 rows into LDS as bf16; 16B chunks, pch = ch ^ (row&15)
    #pragma unroll
    for (int c = 0; c < 4; ++c) {
        int ci = tid + 256 * c;         // 0..1023
        int row = ci >> 4, ch = ci & 15;
        int pch = ch ^ (row & 15);
        if (SRC32) {
            const float* src = (const float*)xsrc + ((long long)(b * N_ + sids[row])) * F_ + ch * 8;
            float4 v0 = *(const float4*)src;
            float4 v1 = *(const float4*)(src + 4);
            ushort4 h0, h1;
            h0.x = f2bf(v0.x); h0.y = f2bf(v0.y); h0.z = f2bf(v0.z); h0.w = f2bf(v0.w);
            h1.x = f2bf(v1.x); h1.y = f2bf(v1.y); h1.z = f2bf(v1.z); h1.w = f2bf(v1.w);
            *(ushort4*)&xt[row * F_ + pch * 8] = h0;
            *(ushort4*)&xt[row * F_ + pch * 8 + 4] = h1;
        } else {
            const int4* src = (const int4*)((const unsigned short*)xsrc +
                                ((long long)(b * N_ + sids[row])) * F_ + ch * 8);
            *(int4*)&xt[row * F_ + pch * 8] = *src;
        }
    }
    __syncthreads();
    int w = tid >> 6, lane = tid & 63;
    int erow = w * 16 + (lane & 15);      // this wave's 16 edges
    short8 bfr[4];
    #pragma unroll
    for (int g = 0; g < 4; ++g) {
        int pch = (g * 4 + (lane >> 4)) ^ (erow & 15);
        bfr[g] = *(const short8*)&xt[erow * F_ + pch * 8];
    }
    int jq = (lane >> 4) * 4;             // j sub-offset of this lane's 4 regs
    long long ebase = ((long long)(b * E_ + e0 + w * 16 + (lane & 15))) * F_;
    #pragma unroll
    for (int nt = 0; nt < 8; ++nt) {
        f32x4 acc = (f32x4){0.f, 0.f, 0.f, 0.f};
        #pragma unroll
        for (int g = 0; g < 4; ++g) {
            short8 afr = *(const short8*)(wf + ((nt * 4 + g) * 64 + lane) * 8);
            acc = __builtin_amdgcn_mfma_f32_16x16x32_bf16(afr, bfr[g], acc, 0, 0, 0);
        }
        float4 bv = *(const float4*)(bias + nt * 16 + jq);
        ushort4 o;
        o.x = f2bf(fast_tanh(acc[0] + bv.x));
        o.y = f2bf(fast_tanh(acc[1] + bv.y));
        o.z = f2bf(fast_tanh(acc[2] + bv.z));
        o.w = f2bf(fast_tanh(acc[3] + bv.w));
        *(ushort4*)(eout + ebase + nt * 16 + jq) = o;
    }
}

// x_next[b,n,:] = sum_k mask * edge_emb[b, ne[n,k], :] / (cnt + eps)
// One wave per node, quarter-wave k-split: quarter qh handles ks 4qh..4qh+3
// (one int4 pne load, 4 x 16B short8 gathers); each lane covers 8 cols.
// Reduce across quarters with shfl_xor(16)+shfl_xor(32). XCD-swizzled:
// XCD x processes only batch x -> ebuf gathers are L2-local.
__global__ void __launch_bounds__(256) agg_kernel(
    const unsigned short* __restrict__ ee, const int* __restrict__ pne,
    const float* __restrict__ x0, float* __restrict__ out,
    unsigned short* __restrict__ xbn, int col_off) {
    int wid = threadIdx.x >> 6, lane = threadIdx.x & 63;
    int swz = (blockIdx.x & 7) * 1024 + (blockIdx.x >> 3);  // batch-per-XCD
    int node = swz * 4 + wid;          // < B*N
    int b = node >> 12;                // N=4096
    if (x0) {
        float2 c = *(const float2*)(x0 + (long long)node * F_ + lane * 2);
        *(float2*)(out + (long long)node * 384 + lane * 2) = c;
    }
    int qh = lane >> 4, s16 = lane & 15;
    int4 q = *(const int4*)(pne + node * K_ + qh * 4);
    float cnt = (float)((q.x >= 0) + (q.y >= 0) + (q.z >= 0) + (q.w >= 0));
    cnt += __shfl_xor(cnt, 16);
    cnt += __shfl_xor(cnt, 32);
    const unsigned short* ebase = ee + (long long)b * (E_ * F_) + s16 * 8;
    float a0 = 0.f, a1 = 0.f, a2 = 0.f, a3 = 0.f;
    float a4 = 0.f, a5 = 0.f, a6 = 0.f, a7 = 0.f;
    #define PROC(pk) { \
        float m = ((pk) >= 0) ? 1.0f : 0.0f; \
        int eid = (pk) < 0 ? 0 : (pk); \
        short8 v = *(const short8*)(ebase + (long long)eid * F_); \
        a0 += m * bf2f((unsigned short)v[0]); a1 += m * bf2f((unsigned short)v[1]); \
        a2 += m * bf2f((unsigned short)v[2]); a3 += m * bf2f((unsigned short)v[3]); \
        a4 += m * bf2f((unsigned short)v[4]); a5 += m * bf2f((unsigned short)v[5]); \
        a6 += m * bf2f((unsigned short)v[6]); a7 += m * bf2f((unsigned short)v[7]); }
    PROC(q.x) PROC(q.y) PROC(q.z) PROC(q.w)
    #undef PROC
    a0 += __shfl_xor(a0, 16); a1 += __shfl_xor(a1, 16);
    a2 += __shfl_xor(a2, 16); a3 += __shfl_xor(a3, 16);
    a4 += __shfl_xor(a4, 16); a5 += __shfl_xor(a5, 16);
    a6 += __shfl_xor(a6, 16); a7 += __shfl_xor(a7, 16);
    a0 += __shfl_xor(a0, 32); a1 += __shfl_xor(a1, 32);
    a2 += __shfl_xor(a2, 32); a3 += __shfl_xor(a3, 32);
    a4 += __shfl_xor(a4, 32); a5 += __shfl_xor(a5, 32);
    a6 += __shfl_xor(a6, 32); a7 += __shfl_xor(a7, 32);
    if (qh == 0) {
        float inv = 1.0f / (cnt + 1e-8f);
        a0 *= inv; a1 *= inv; a2 *= inv; a3 *= inv;
        a4 *= inv; a5 *= inv; a6 *= inv; a7 *= inv;
        float* po = out + (long long)node * 384 + col_off + s16 * 8;
        float4 o0; o0.x = a0; o0.y = a1; o0.z = a2; o0.w = a3;
        float4 o1; o1.x = a4; o1.y = a5; o1.z = a6; o1.w = a7;
        *(float4*)po = o0;
        *(float4*)(po + 4) = o1;
        if (xbn) {
            short8 h;
            h[0] = (short)f2bf(a0); h[1] = (short)f2bf(a1);
            h[2] = (short)f2bf(a2); h[3] = (short)f2bf(a3);
            h[4] = (short)f2bf(a4); h[5] = (short)f2bf(a5);
            h[6] = (short)f2bf(a6); h[7] = (short)f2bf(a7);
            *(short8*)(xbn + (long long)node * F_ + s16 * 8) = h;
        }
    }
}

extern "C" void kernel_launch(void* const* d_in, const int* in_sizes, int n_in,
                              void* d_out, int out_size, void* d_ws, size_t ws_size,
                              hipStream_t stream) {
    const float* x0        = (const float*)d_in[0];
    const int*   edges_raw = (const int*)d_in[1];
    const int*   ne_raw    = (const int*)d_in[2];
    const int*   mask      = (const int*)d_in[3];
    const float* W1        = (const float*)d_in[4];
    const float* b1        = (const float*)d_in[5];
    const float* W2        = (const float*)d_in[6];
    const float* b2        = (const float*)d_in[7];
    float* out = (float*)d_out;
    char* ws = (char*)d_ws;

    unsigned short* ebuf = (unsigned short*)ws;                   // B*E*F bf16 = 32 MB
    unsigned short* x1b  = (unsigned short*)(ws + 33554432);      // B*N*F bf16 = 8 MB
    unsigned short* wf   = (unsigned short*)(ws + 41943040);      // 2*128*128  = 64 KB
    int* sender32        = (int*)(ws + 42008576);                 // B*E int32  = 512 KB
    int* pne             = (int*)(ws + 42532864);                 // B*N*K      = 2 MB

    prep_idx<<<2576, 256, 0, stream>>>(edges_raw, ne_raw, mask, W1, W2,
                                       sender32, pne, wf);
    // round 1: edge transform from fp32 x0, agg also copies x0 -> out[:,0:128]
    edge_kernel<1><<<2048, 256, 0, stream>>>(x0, sender32, wf, b1, ebuf);
    agg_kernel<<<8192, 256, 0, stream>>>(ebuf, pne, x0, out, x1b, 128);
    // round 2
    edge_kernel<0><<<2048, 256, 0, stream>>>(x1b, sender32, wf + 16384, b2, ebuf);
    agg_kernel<<<8192, 256, 0, stream>>>(ebuf, pne, nullptr, out, nullptr, 256);
}